// Round 1
// baseline (150.064 us; speedup 1.0000x reference)
//
#include <hip/hip_runtime.h>
#include <math.h>

// Problem constants (from reference): B=32, N=100000, D=3, CDIM=128
#define NBATCH 32
#define NPTS   100000
#define CD     128
#define PPT    8   // points per thread in main kernel; N % PPT == 0

// 2*log2(e): pre-folded into M'/v' so tanh uses exp2 directly.
#define C2LOG2E 2.8853900817779268f

#if defined(__has_builtin)
#if __has_builtin(__builtin_amdgcn_exp2f)
#define FAST_EXP2(v) __builtin_amdgcn_exp2f(v)
#endif
#endif
#ifndef FAST_EXP2
#define FAST_EXP2(v) __expf((v) * 0.6931471805599453f)
#endif

// yp = 2*log2(e) * y ; returns tanh(y) = 1 - 2/(2^yp + 1)
__device__ __forceinline__ float tanh_pre(float yp) {
    yp = fminf(fmaxf(yp, -30.0f), 30.0f);   // |y| <= ~10.4, tanh saturated to 1 ulp
    float e = FAST_EXP2(yp);
    float r = __builtin_amdgcn_rcpf(e + 1.0f);
    return fmaf(-2.0f, r, 1.0f);
}

// Kernel 1: per (batch, tag, d) compute the fused affine params.
// params layout: for b in [0,32), tag in [0,3): 12 floats at (b*3+tag)*12
//   [0..8]  = M' row-major (C2*scale_d*W[d][k])
//   [9..11] = v'            (C2*(b[d]*scale_d + bias_d))
__global__ void film_params_kernel(
    const float* __restrict__ c,
    const float* __restrict__ W0, const float* __restrict__ b0,
    const float* __restrict__ Ws0, const float* __restrict__ bs0,
    const float* __restrict__ Wb0, const float* __restrict__ bb0,
    const float* __restrict__ W1, const float* __restrict__ b1,
    const float* __restrict__ Ws1, const float* __restrict__ bs1,
    const float* __restrict__ Wb1, const float* __restrict__ bb1,
    const float* __restrict__ W2, const float* __restrict__ b2,
    const float* __restrict__ Ws2, const float* __restrict__ bs2,
    const float* __restrict__ Wb2, const float* __restrict__ bb2,
    float* __restrict__ params)
{
    int idx = blockIdx.x * blockDim.x + threadIdx.x;
    if (idx >= NBATCH * 3 * 3) return;
    int d   = idx % 3;
    int tag = (idx / 3) % 3;
    int b   = idx / 9;

    const float* Wt[3]  = {W0, W1, W2};
    const float* bt[3]  = {b0, b1, b2};
    const float* Wst[3] = {Ws0, Ws1, Ws2};
    const float* bst[3] = {bs0, bs1, bs2};
    const float* Wbt[3] = {Wb0, Wb1, Wb2};
    const float* bbt[3] = {bb0, bb1, bb2};

    const float* crow  = c + b * CD;
    const float* wsrow = Wst[tag] + d * CD;
    const float* wbrow = Wbt[tag] + d * CD;
    float sacc = bst[tag][d];   // -> scale pre-activation
    float bacc = bbt[tag][d];   // -> bias
    for (int k = 0; k < CD; ++k) {
        float cv = crow[k];
        sacc = fmaf(cv, wsrow[k], sacc);
        bacc = fmaf(cv, wbrow[k], bacc);
    }
    float scale = 1.0f / (1.0f + expf(-sacc));   // sigmoid
    float cs = C2LOG2E * scale;

    float* o = params + (b * 3 + tag) * 12;
    o[d * 3 + 0] = cs * Wt[tag][d * 3 + 0];
    o[d * 3 + 1] = cs * Wt[tag][d * 3 + 1];
    o[d * 3 + 2] = cs * Wt[tag][d * 3 + 2];
    o[9 + d]     = C2LOG2E * (bt[tag][d] * scale + bacc);
}

// Kernel 2: elementwise chain. Each thread: 8 points (24 floats = 6 float4).
__global__ __launch_bounds__(256) void film_main_kernel(
    const float* __restrict__ x, const float* __restrict__ params,
    float* __restrict__ out, int nthreads)
{
    int t = blockIdx.x * blockDim.x + threadIdx.x;
    if (t >= nthreads) return;
    int p0 = t * PPT;            // first point; all PPT points share batch b
    int b  = p0 / NPTS;

    const float* P = params + b * 36;
    float M0[9], M1[9], M2[9], v0[3], v1[3], v2[3];
#pragma unroll
    for (int i = 0; i < 9; ++i) { M0[i] = P[i]; M1[i] = P[12 + i]; M2[i] = P[24 + i]; }
#pragma unroll
    for (int i = 0; i < 3; ++i) { v0[i] = P[9 + i]; v1[i] = P[21 + i]; v2[i] = P[33 + i]; }

    float a[3 * PPT];
    const float4* xin = (const float4*)(x + (size_t)p0 * 3);
#pragma unroll
    for (int i = 0; i < (3 * PPT) / 4; ++i) ((float4*)a)[i] = xin[i];

#define APPLY(M, v)                                                       \
    {                                                                     \
        float y0 = fmaf(M[0], h0, fmaf(M[1], h1, fmaf(M[2], h2, v[0]))); \
        float y1 = fmaf(M[3], h0, fmaf(M[4], h1, fmaf(M[5], h2, v[1]))); \
        float y2 = fmaf(M[6], h0, fmaf(M[7], h1, fmaf(M[8], h2, v[2]))); \
        h0 = tanh_pre(y0); h1 = tanh_pre(y1); h2 = tanh_pre(y2);         \
    }

#pragma unroll
    for (int p = 0; p < PPT; ++p) {
        float h0 = a[p * 3 + 0], h1 = a[p * 3 + 1], h2 = a[p * 3 + 2];
        APPLY(M0, v0);
        APPLY(M1, v1);
#pragma unroll
        for (int r = 0; r < 4; ++r) { APPLY(M2, v2); }
        a[p * 3 + 0] = h0; a[p * 3 + 1] = h1; a[p * 3 + 2] = h2;
    }
#undef APPLY

    float4* op = (float4*)(out + (size_t)p0 * 3);
#pragma unroll
    for (int i = 0; i < (3 * PPT) / 4; ++i) op[i] = ((float4*)a)[i];
}

extern "C" void kernel_launch(void* const* d_in, const int* in_sizes, int n_in,
                              void* d_out, int out_size, void* d_ws, size_t ws_size,
                              hipStream_t stream)
{
    // Input order: t, x, c, then per tag {W, b, Ws, bs, Wb, bb} for tags 0,1,2
    const float* x = (const float*)d_in[1];
    const float* c = (const float*)d_in[2];
    float* params = (float*)d_ws;   // 32*3*12 floats = 4608 B

    film_params_kernel<<<dim3(5), dim3(64), 0, stream>>>(
        c,
        (const float*)d_in[3],  (const float*)d_in[4],  (const float*)d_in[5],
        (const float*)d_in[6],  (const float*)d_in[7],  (const float*)d_in[8],
        (const float*)d_in[9],  (const float*)d_in[10], (const float*)d_in[11],
        (const float*)d_in[12], (const float*)d_in[13], (const float*)d_in[14],
        (const float*)d_in[15], (const float*)d_in[16], (const float*)d_in[17],
        (const float*)d_in[18], (const float*)d_in[19], (const float*)d_in[20],
        params);

    int nthreads = (NBATCH * NPTS) / PPT;            // 400000
    int grid = (nthreads + 255) / 256;               // 1563
    film_main_kernel<<<dim3(grid), dim3(256), 0, stream>>>(
        x, params, (float*)d_out, nthreads);
}

// Round 2
// 144.005 us; speedup vs baseline: 1.0421x; 1.0421x over previous
//
#include <hip/hip_runtime.h>
#include <math.h>

// Problem constants: B=32, N=100000, D=3, CDIM=128
#define NBATCH 32
#define NPTS   100000
#define CD     128
#define PPT    8                          // points per thread; NPTS % PPT == 0
#define TPB    256
#define THREADS_PER_BATCH (NPTS / PPT)    // 12500
#define BLKS_PER_BATCH 49                 // ceil(12500/256)

#define C2LOG2E 2.8853900817779268f       // 2*log2(e), pre-folded into params
#define LOG2E   1.4426950408889634f

// yp = 2*log2(e)*y ; tanh(y) = 1 - 2/(2^yp + 1).
// No clamp needed: exp2 overflow->inf gives rcp->0 -> +1; underflow->0 -> -1.
__device__ __forceinline__ float tanh_pre(float yp) {
    float e = __builtin_amdgcn_exp2f(yp);
    float r = __builtin_amdgcn_rcpf(e + 1.0f);
    return fmaf(-2.0f, r, 1.0f);
}

__global__ __launch_bounds__(TPB) void film_fused_kernel(
    const float* __restrict__ x, const float* __restrict__ c,
    const float* __restrict__ W0, const float* __restrict__ b0,
    const float* __restrict__ Ws0, const float* __restrict__ bs0,
    const float* __restrict__ Wb0, const float* __restrict__ bb0,
    const float* __restrict__ W1, const float* __restrict__ b1,
    const float* __restrict__ Ws1, const float* __restrict__ bs1,
    const float* __restrict__ Wb1, const float* __restrict__ bb1,
    const float* __restrict__ W2, const float* __restrict__ b2,
    const float* __restrict__ Ws2, const float* __restrict__ bs2,
    const float* __restrict__ Wb2, const float* __restrict__ bb2,
    float* __restrict__ out)
{
    __shared__ float lds_part[18][8];
    __shared__ float lds_red[18];
    __shared__ float lds_params[36];   // 3 tags x (9 M' + 3 v'), 16B-aligned blocks

    const int tid = threadIdx.x;
    const int blk = blockIdx.x;
    const int b = blk / BLKS_PER_BATCH;
    const int blk_in_b = blk - b * BLKS_PER_BATCH;

    // ---- Prologue: 18 dot-products (tag x d x {scale,bias}) of length 128 ----
    if (tid < 144) {
        const int g = tid >> 3, j = tid & 7;        // 18 groups x 8 threads
        const int tag = g / 6;
        const int r = g - tag * 6;
        const int d = r >> 1, which = r & 1;        // which: 0=Ws, 1=Wb
        const float* Wsel;
        if (tag == 0)      Wsel = which ? Wb0 : Ws0;
        else if (tag == 1) Wsel = which ? Wb1 : Ws1;
        else               Wsel = which ? Wb2 : Ws2;
        const float4* row4 = (const float4*)(Wsel + d * CD);
        const float4* c4   = (const float4*)(c + b * CD);
        float acc = 0.0f;
#pragma unroll
        for (int i = 0; i < 4; ++i) {               // 16 elements per thread
            float4 cv = c4[j * 4 + i];
            float4 wv = row4[j * 4 + i];
            acc = fmaf(cv.x, wv.x, acc);
            acc = fmaf(cv.y, wv.y, acc);
            acc = fmaf(cv.z, wv.z, acc);
            acc = fmaf(cv.w, wv.w, acc);
        }
        lds_part[g][j] = acc;
    }
    __syncthreads();
    if (tid < 18) {
        float s = 0.0f;
#pragma unroll
        for (int j = 0; j < 8; ++j) s += lds_part[tid][j];
        lds_red[tid] = s;
    }
    __syncthreads();
    if (tid < 9) {
        const int tag = tid / 3, d = tid - tag * 3;
        const float *Wt, *bt, *bst, *bbt;
        if (tag == 0)      { Wt = W0; bt = b0; bst = bs0; bbt = bb0; }
        else if (tag == 1) { Wt = W1; bt = b1; bst = bs1; bbt = bb1; }
        else               { Wt = W2; bt = b2; bst = bs2; bbt = bb2; }
        float sacc = lds_red[tag * 6 + d * 2 + 0] + bst[d];
        float bacc = lds_red[tag * 6 + d * 2 + 1] + bbt[d];
        float scale = 1.0f / (1.0f + __builtin_amdgcn_exp2f(-sacc * LOG2E));
        float cs = C2LOG2E * scale;
        float* o = lds_params + tag * 12;
        o[d * 3 + 0] = cs * Wt[d * 3 + 0];
        o[d * 3 + 1] = cs * Wt[d * 3 + 1];
        o[d * 3 + 2] = cs * Wt[d * 3 + 2];
        o[9 + d]     = C2LOG2E * fmaf(bt[d], scale, bacc);
    }
    __syncthreads();

    // ---- Broadcast params LDS -> registers (uniform addr: conflict-free) ----
    float M0[9], M1[9], M2[9], v0[3], v1[3], v2[3];
    {
        const float4* P = (const float4*)lds_params;
        float4 q;
        q = P[0]; M0[0]=q.x; M0[1]=q.y; M0[2]=q.z; M0[3]=q.w;
        q = P[1]; M0[4]=q.x; M0[5]=q.y; M0[6]=q.z; M0[7]=q.w;
        q = P[2]; M0[8]=q.x; v0[0]=q.y; v0[1]=q.z; v0[2]=q.w;
        q = P[3]; M1[0]=q.x; M1[1]=q.y; M1[2]=q.z; M1[3]=q.w;
        q = P[4]; M1[4]=q.x; M1[5]=q.y; M1[6]=q.z; M1[7]=q.w;
        q = P[5]; M1[8]=q.x; v1[0]=q.y; v1[1]=q.z; v1[2]=q.w;
        q = P[6]; M2[0]=q.x; M2[1]=q.y; M2[2]=q.z; M2[3]=q.w;
        q = P[7]; M2[4]=q.x; M2[5]=q.y; M2[6]=q.z; M2[7]=q.w;
        q = P[8]; M2[8]=q.x; v2[0]=q.y; v2[1]=q.z; v2[2]=q.w;
    }

    const int t_local = blk_in_b * TPB + tid;
    if (t_local >= THREADS_PER_BATCH) return;       // tail block; no more barriers

    const size_t p0 = (size_t)b * NPTS + (size_t)t_local * PPT;

    float a[3 * PPT];
    const float4* xin = (const float4*)(x + p0 * 3);
#pragma unroll
    for (int i = 0; i < (3 * PPT) / 4; ++i) ((float4*)a)[i] = xin[i];

#define APPLY(M, v)                                                       \
    {                                                                     \
        float y0 = fmaf(M[0], h0, fmaf(M[1], h1, fmaf(M[2], h2, v[0]))); \
        float y1 = fmaf(M[3], h0, fmaf(M[4], h1, fmaf(M[5], h2, v[1]))); \
        float y2 = fmaf(M[6], h0, fmaf(M[7], h1, fmaf(M[8], h2, v[2]))); \
        h0 = tanh_pre(y0); h1 = tanh_pre(y1); h2 = tanh_pre(y2);         \
    }

#pragma unroll
    for (int p = 0; p < PPT; ++p) {
        float h0 = a[p * 3 + 0], h1 = a[p * 3 + 1], h2 = a[p * 3 + 2];
        APPLY(M0, v0);
        APPLY(M1, v1);
#pragma unroll
        for (int r = 0; r < 4; ++r) { APPLY(M2, v2); }
        a[p * 3 + 0] = h0; a[p * 3 + 1] = h1; a[p * 3 + 2] = h2;
    }
#undef APPLY

    float4* op = (float4*)(out + p0 * 3);
#pragma unroll
    for (int i = 0; i < (3 * PPT) / 4; ++i) op[i] = ((float4*)a)[i];
}

extern "C" void kernel_launch(void* const* d_in, const int* in_sizes, int n_in,
                              void* d_out, int out_size, void* d_ws, size_t ws_size,
                              hipStream_t stream)
{
    // Input order: t, x, c, then per tag {W, b, Ws, bs, Wb, bb} for tags 0,1,2
    film_fused_kernel<<<dim3(NBATCH * BLKS_PER_BATCH), dim3(TPB), 0, stream>>>(
        (const float*)d_in[1],  (const float*)d_in[2],
        (const float*)d_in[3],  (const float*)d_in[4],  (const float*)d_in[5],
        (const float*)d_in[6],  (const float*)d_in[7],  (const float*)d_in[8],
        (const float*)d_in[9],  (const float*)d_in[10], (const float*)d_in[11],
        (const float*)d_in[12], (const float*)d_in[13], (const float*)d_in[14],
        (const float*)d_in[15], (const float*)d_in[16], (const float*)d_in[17],
        (const float*)d_in[18], (const float*)d_in[19], (const float*)d_in[20],
        (float*)d_out);
}